// Round 8
// baseline (915.852 us; speedup 1.0000x reference)
//
#include <hip/hip_runtime.h>

typedef unsigned short u16;
typedef __attribute__((ext_vector_type(4))) float f32x4;
typedef __attribute__((ext_vector_type(8))) short s16x8;

#define T_TOK 8192
#define HD    1024
#define ID    4096
#define NE    8
#define AK    (T_TOK * 2)      // total assignments (top-2)
#define APAD  (AK + 256)       // slack rows for 256-row A tiles
#define MTMAX 72               // max M-tiles: 16384/256 + 8 partials

#define BAR()   __builtin_amdgcn_s_barrier()
#define SB0()   __builtin_amdgcn_sched_barrier(0)
#define PRIO1() __builtin_amdgcn_s_setprio(1)
#define PRIO0() __builtin_amdgcn_s_setprio(0)
#define WAITV6() asm volatile("s_waitcnt vmcnt(6)" ::: "memory")
#define WAITV8() asm volatile("s_waitcnt vmcnt(8)" ::: "memory")
#define LGKM0()  do { asm volatile("s_waitcnt lgkmcnt(0)" ::: "memory"); SB0(); } while (0)

__device__ __forceinline__ u16 f2bf(float f) {
  unsigned u = __builtin_bit_cast(unsigned, f);
  u += 0x7FFFu + ((u >> 16) & 1u);   // round-to-nearest-even
  return (u16)(u >> 16);
}

__device__ __forceinline__ float bf2f(u16 v) {
  unsigned u = (unsigned)v << 16;
  return __builtin_bit_cast(float, u);
}

__device__ __forceinline__ void gld16(u16* lds, const u16* g) {
  __builtin_amdgcn_global_load_lds(
      (const __attribute__((address_space(1))) unsigned int*)g,
      (__attribute__((address_space(3))) unsigned int*)lds, 16, 0, 0);
}

// ---------------- routing helpers ----------------

__global__ void k_init(int* counts) {
  if (threadIdx.x < NE) counts[threadIdx.x] = 0;
}

__global__ void k_offsets(const int* __restrict__ counts, int* offs, int* cursors,
                          int* __restrict__ tiles, int* __restrict__ ntile) {
  if (threadIdx.x == 0) {
    int s = 0;
    for (int e = 0; e < NE; ++e) { offs[e] = s; s += counts[e]; }
    offs[NE] = s;
    int nt = 0;
    for (int e = 0; e < NE; ++e)
      for (int m0 = 0; m0 < counts[e]; m0 += 256)
        tiles[nt++] = (e << 16) | (m0 >> 8);
    ntile[0] = nt;
    for (int i = nt; i < MTMAX; ++i) tiles[i] = 0;
  }
  if (threadIdx.x < NE) cursors[threadIdx.x] = 0;
}

__global__ __launch_bounds__(256) void k_scatter(
    const int* __restrict__ tidx, const int* __restrict__ offs,
    int* cursors, int* __restrict__ list, int* __restrict__ pos) {
  int idx = blockIdx.x * 256 + threadIdx.x;
  if (idx >= AK) return;
  int e = tidx[idx];
  int p = atomicAdd(&cursors[e], 1);
  int a = offs[e] + p;
  list[a] = idx >> 1;
  pos[idx] = a;
}

// -------- unified transpose tile: in [R][C] fp32 -> out [C'][R] bf16 --------
// R-block = 256 (input rows, becomes 512B-contiguous out runs), C-block = 64.
// LDS tile[64][264] u16 with chunk-XOR swizzle: element (c, r) stored at
// tile[c][ ((r>>3)^(c&7))<<3 | (r&7) ] — bijective, 16B-aligned drain reads.

__device__ __forceinline__ void tconv_block(
    const float* __restrict__ in, u16* __restrict__ out,
    int R, int C, int r0, int c0, int which, int interleave, char* smem) {
  u16 (*tile)[264] = (u16(*)[264])smem;
  int t = threadIdx.x;
  int rr = t >> 4;            // 0..15
  int cc4 = (t & 15) * 4;
#pragma unroll
  for (int i = 0; i < 16; ++i) {
    int r = i * 16 + rr;      // 0..255
    float4 v = *(const float4*)&in[(size_t)(r0 + r) * C + c0 + cc4];
    u16 bv[4] = {f2bf(v.x), f2bf(v.y), f2bf(v.z), f2bf(v.w)};
#pragma unroll
    for (int q = 0; q < 4; ++q) {
      int c = cc4 + q;
      tile[c][(((r >> 3) ^ (c & 7)) << 3) | (r & 7)] = bv[q];
    }
  }
  __syncthreads();
  int c = t >> 2;             // 0..63
  int ro = (t & 3) * 64;      // 0,64,128,192
  int gc = c0 + c;
  int orow = interleave ? (((gc >> 4) << 5) + which * 16 + (gc & 15)) : gc;
  u16* obase = out + (size_t)orow * R + r0;
#pragma unroll
  for (int j = 0; j < 8; ++j) {
    int roff = ro + j * 8;
    int phys = (((roff >> 3) ^ (c & 7)) << 3);
    *(s16x8*)&obase[roff] = *(const s16x8*)&tile[c][phys];
  }
}

// ---------------- prepA: cvtx + w13 transpose + router ----------------
#define NBA_CVT 4096
#define NBA_T13 4096

__global__ __launch_bounds__(256) void k_prepA(
    const float* __restrict__ x, const float* __restrict__ wg,
    const float* __restrict__ w1, const float* __restrict__ w3,
    u16* __restrict__ xb, u16* __restrict__ w13b,
    int* __restrict__ tidx, float* __restrict__ tw, int* __restrict__ counts) {
  __shared__ char smem[64 * 264 * 2];
  int bid = blockIdx.x, t = threadIdx.x;

  if (bid < NBA_CVT) {                       // ---- cvtx: 8 floats/thread
    int idx = bid * 256 + t;
    float4 v0 = ((const float4*)x)[idx * 2];
    float4 v1 = ((const float4*)x)[idx * 2 + 1];
    s16x8 o;
    o[0] = (short)f2bf(v0.x); o[1] = (short)f2bf(v0.y);
    o[2] = (short)f2bf(v0.z); o[3] = (short)f2bf(v0.w);
    o[4] = (short)f2bf(v1.x); o[5] = (short)f2bf(v1.y);
    o[6] = (short)f2bf(v1.z); o[7] = (short)f2bf(v1.w);
    ((s16x8*)xb)[idx] = o;
    return;
  }
  if (bid < NBA_CVT + NBA_T13) {             // ---- w1/w3 [H][I] -> w13b [2I][H]
    int r = bid - NBA_CVT;
    int bx = r & 63;                         // I/64
    int by = (r >> 6) & 3;                   // H/256
    int bz = r >> 8;                         // 2E
    int which = bz >> 3, e = bz & 7;
    const float* in = (which ? w3 : w1) + (size_t)e * HD * ID;
    tconv_block(in, w13b + (size_t)e * 2 * ID * HD,
                HD, ID, by * 256, bx * 64, which, 1, smem);
    return;
  }
  {                                          // ---- router
    float* wgs = (float*)smem;               // [e][h] transposed, 32 KB
    int blockR = bid - NBA_CVT - NBA_T13;
    for (int i = t; i < NE * HD; i += 256) {
      int h = i >> 3, e = i & 7;
      wgs[e * HD + h] = wg[i];
    }
    __syncthreads();
    int lane = t & 63, wid = t >> 6;
    int tok = blockR * 4 + wid;
    const float* xr = x + (size_t)tok * HD;
    double acc[NE];
#pragma unroll
    for (int e = 0; e < NE; ++e) acc[e] = 0.0;
    for (int i = 0; i < HD / 64; ++i) {
      float xv = xr[lane + i * 64];
#pragma unroll
      for (int e = 0; e < NE; ++e)
        acc[e] += (double)xv * (double)wgs[e * HD + lane + i * 64];
    }
#pragma unroll
    for (int e = 0; e < NE; ++e)
      for (int s = 32; s >= 1; s >>= 1) acc[e] += __shfl_xor(acc[e], s, 64);
    int e0 = 0; double m0 = acc[0];
    for (int e = 1; e < NE; ++e) if (acc[e] > m0) { m0 = acc[e]; e0 = e; }
    int e1 = -1; double m1 = -1e300;
    for (int e = 0; e < NE; ++e) if (e != e0 && acc[e] > m1) { m1 = acc[e]; e1 = e; }
    if (lane == 0) {
      double d = exp(m1 - m0);
      tidx[tok * 2] = e0; tidx[tok * 2 + 1] = e1;
      tw[tok * 2] = (float)(1.0 / (1.0 + d));
      tw[tok * 2 + 1] = (float)(d / (1.0 + d));
      atomicAdd(&counts[e0], 1);
      atomicAdd(&counts[e1], 1);
    }
  }
}

// ---------------- prepB: w2 [E][I][H] -> w2b [E][H][I] ----------------
__global__ __launch_bounds__(256) void k_prepB(
    const float* __restrict__ w2, u16* __restrict__ w2b) {
  __shared__ char smem[64 * 264 * 2];
  int bid = blockIdx.x;
  int bx = bid & 15;                         // H/64
  int by = (bid >> 4) & 15;                  // I/256
  int e = bid >> 8;
  tconv_block(w2 + (size_t)e * ID * HD, w2b + (size_t)e * HD * ID,
              ID, HD, by * 256, bx * 64, 0, 0, smem);
}

// ============ 8-phase GEMM core (256x256x64, 8 waves 2Mx4N) ============
// mf(): kk=0 cluster (8 independent MFMA) then kk=1 cluster — dependency
// distance 8 to cover MFMA latency at 2 waves/SIMD.

#define GEMM_CORE(NTK, NITER) \
  int wr = wid >> 2, wc = wid & 3; \
  int lane15 = lane & 15, lq = lane >> 4, sw8 = lane15 & 7; \
  f32x4 acc[8][4]; \
  _Pragma("unroll") for (int m = 0; m < 8; ++m) \
    _Pragma("unroll") for (int n = 0; n < 4; ++n) acc[m][n] = (f32x4){0.f,0.f,0.f,0.f}; \
  auto stgA = [&](int bb, int h, int kt) { \
    gld16(&As[bb][(h*128 + 0*64 + wid*8) * 64], gA[h*2+0] + kt*64); \
    gld16(&As[bb][(h*128 + 1*64 + wid*8) * 64], gA[h*2+1] + kt*64); }; \
  auto stgB = [&](int bb, int h, int kt) { \
    gld16(&Bs[bb][(h*128 + 0*64 + wid*8) * 64], gB[h*2+0] + kt*64); \
    gld16(&Bs[bb][(h*128 + 1*64 + wid*8) * 64], gB[h*2+1] + kt*64); }; \
  s16x8 a[4][2], b[4][2]; \
  auto rdA = [&](int bb, int mh) { \
    _Pragma("unroll") for (int mm = 0; mm < 4; ++mm) \
      _Pragma("unroll") for (int kk = 0; kk < 2; ++kk) \
        a[mm][kk] = *(const s16x8*)&As[bb][(mh*128 + wr*64 + mm*16 + lane15)*64 + (((kk*4+lq)^sw8)*8)]; }; \
  auto rdB = [&](int bb, int fh) { \
    _Pragma("unroll") for (int ff = 0; ff < 2; ++ff) \
      _Pragma("unroll") for (int kk = 0; kk < 2; ++kk) \
        b[fh*2+ff][kk] = *(const s16x8*)&Bs[bb][(fh*128 + wc*32 + ff*16 + lane15)*64 + (((kk*4+lq)^sw8)*8)]; }; \
  auto mf = [&](int mh, int fh) { \
    _Pragma("unroll") for (int kk = 0; kk < 2; ++kk) \
      _Pragma("unroll") for (int mm = 0; mm < 4; ++mm) \
        _Pragma("unroll") for (int ff = 0; ff < 2; ++ff) \
          acc[mh*4+mm][fh*2+ff] = __builtin_amdgcn_mfma_f32_16x16x32_bf16(a[mm][kk], b[fh*2+ff][kk], acc[mh*4+mm][fh*2+ff], 0, 0, 0); }; \
  /* prologue */ \
  stgA(0,0,0); stgB(0,0,0); stgA(0,1,0); stgB(0,1,0); stgA(1,0,1); stgB(1,0,1); \
  WAITV8(); BAR(); SB0(); \
  for (int i = 0; i < (NITER); ++i) { \
    int ku2 = (2*i+2) & ((NTK)-1), ku3 = (2*i+3) & ((NTK)-1); \
    /* p1 */ rdA(0,0); rdB(0,0); stgA(1,1,2*i+1); WAITV6(); BAR(); LGKM0(); PRIO1(); mf(0,0); PRIO0(); BAR(); SB0(); \
    /* p2 */ rdB(0,1); stgB(1,1,2*i+1); BAR(); LGKM0(); PRIO1(); mf(0,1); PRIO0(); BAR(); SB0(); \
    /* p3 */ rdA(0,1); stgA(0,0,ku2); BAR(); LGKM0(); PRIO1(); mf(1,0); PRIO0(); BAR(); SB0(); \
    /* p4 */ stgB(0,0,ku2); WAITV8(); BAR(); PRIO1(); mf(1,1); PRIO0(); BAR(); SB0(); \
    /* p5 */ rdA(1,0); rdB(1,0); stgA(0,1,ku2); WAITV6(); BAR(); LGKM0(); PRIO1(); mf(0,0); PRIO0(); BAR(); SB0(); \
    /* p6 */ rdB(1,1); stgB(0,1,ku2); BAR(); LGKM0(); PRIO1(); mf(0,1); PRIO0(); BAR(); SB0(); \
    /* p7 */ rdA(1,1); stgA(1,0,ku3); BAR(); LGKM0(); PRIO1(); mf(1,0); PRIO0(); BAR(); SB0(); \
    /* p8 */ stgB(1,0,ku3); WAITV8(); BAR(); PRIO1(); mf(1,1); PRIO0(); BAR(); SB0(); \
  }

// ---- GEMM1: hidden = silu(x@w1)*(x@w3); B = interleaved w13; gathered A ----
__global__ __launch_bounds__(512, 1) void k_gemm1(
    const u16* __restrict__ xb, const u16* __restrict__ w13b,
    const int* __restrict__ list, const int* __restrict__ offs,
    const int* __restrict__ tiles, const int* __restrict__ ntile,
    u16* __restrict__ hidden) {
  int ti = blockIdx.y;
  if (ti >= ntile[0]) return;
  int packed = tiles[ti];
  int e = packed >> 16;
  int m0 = (packed & 0xFFFF) << 8;
  int aoff = offs[e];
  int cnt = offs[e + 1] - aoff;
  int n0 = blockIdx.x * 256;          // over 2I interleaved

  __shared__ u16 As[2][256 * 64];
  __shared__ u16 Bs[2][256 * 64];

  int tid = threadIdx.x, lane = tid & 63, wid = tid >> 6;
  int l8 = lane >> 3, c8 = lane & 7;
  int csrc = (c8 ^ l8) * 8;

  const u16* gA[4]; const u16* gB[4];
#pragma unroll
  for (int h = 0; h < 2; ++h)
#pragma unroll
    for (int c = 0; c < 2; ++c) {
      int row = h * 128 + c * 64 + wid * 8 + l8;
      int rr = m0 + row; if (rr > cnt - 1) rr = cnt - 1;
      gA[h*2+c] = xb + (size_t)list[aoff + rr] * HD + csrc;
      gB[h*2+c] = w13b + ((size_t)e * 2 * ID + n0 + row) * HD + csrc;
    }

  GEMM_CORE(HD / 64, HD / 128)

#pragma unroll
  for (int mh = 0; mh < 2; ++mh)
#pragma unroll
    for (int mm = 0; mm < 4; ++mm)
#pragma unroll
      for (int j = 0; j < 4; ++j) {
        int grow = m0 + mh * 128 + wr * 64 + mm * 16 + lq * 4 + j;
        if (grow < cnt) {
          size_t rbase = (size_t)(aoff + grow) * ID;
#pragma unroll
          for (int p = 0; p < 2; ++p) {
            float v1 = acc[mh*4+mm][2*p][j];
            float v3 = acc[mh*4+mm][2*p+1][j];
            float s = v1 / (1.0f + __expf(-v1));
            int icol = ((n0 + p * 128 + wc * 32) >> 1) + lane15;
            hidden[rbase + icol] = f2bf(s * v3);
          }
        }
      }
}

// ---- GEMM2: yp[kchunk][a] = hidden_chunk @ w2_chunk (bf16 partials) ----
__global__ __launch_bounds__(512, 1) void k_gemm2(
    const u16* __restrict__ hidden, const u16* __restrict__ w2b,
    const int* __restrict__ offs, const int* __restrict__ tiles,
    const int* __restrict__ ntile,
    u16* __restrict__ yp0, u16* __restrict__ yp3) {
  int ti = blockIdx.y;
  if (ti >= ntile[0]) return;
  int packed = tiles[ti];
  int e = packed >> 16;
  int m0 = (packed & 0xFFFF) << 8;
  int aoff = offs[e];
  int cnt = offs[e + 1] - aoff;
  int n0 = (blockIdx.x & 3) * 256;    // H cols
  int kidx = blockIdx.x >> 2;
  int kc = kidx * 1024;               // K chunk base (elements)

  __shared__ u16 As[2][256 * 64];
  __shared__ u16 Bs[2][256 * 64];

  int tid = threadIdx.x, lane = tid & 63, wid = tid >> 6;
  int l8 = lane >> 3, c8 = lane & 7;
  int csrc = (c8 ^ l8) * 8;

  const u16* gA[4]; const u16* gB[4];
#pragma unroll
  for (int h = 0; h < 2; ++h)
#pragma unroll
    for (int c = 0; c < 2; ++c) {
      int row = h * 128 + c * 64 + wid * 8 + l8;
      gA[h*2+c] = hidden + (size_t)(aoff + m0 + row) * ID + kc + csrc;  // APAD slack
      gB[h*2+c] = w2b + ((size_t)e * HD + n0 + row) * ID + kc + csrc;
    }

  GEMM_CORE(1024 / 64, 1024 / 128)

  u16* yp = (kidx < 3) ? yp0 + (size_t)kidx * AK * HD : yp3;
#pragma unroll
  for (int mh = 0; mh < 2; ++mh)
#pragma unroll
    for (int mm = 0; mm < 4; ++mm)
#pragma unroll
      for (int j = 0; j < 4; ++j) {
        int grow = m0 + mh * 128 + wr * 64 + mm * 16 + lq * 4 + j;
        if (grow < cnt) {
          u16* yrow = yp + (size_t)(aoff + grow) * HD;
#pragma unroll
          for (int f = 0; f < 4; ++f) {
            int col = n0 + (f >> 1) * 128 + wc * 32 + (f & 1) * 16 + lane15;
            yrow[col] = f2bf(acc[mh*4+mm][f][j]);
          }
        }
      }
}

// ---- combine: out[t] = w0*sum_k yp[k][p0] + w1*sum_k yp[k][p1] ----
__global__ __launch_bounds__(256) void k_combine(
    const u16* __restrict__ yp0, const u16* __restrict__ yp3,
    const int* __restrict__ pos, const float* __restrict__ tw,
    float* __restrict__ out) {
  int t = blockIdx.x;
  int c = threadIdx.x * 4;
  int a0 = pos[t * 2], a1 = pos[t * 2 + 1];
  float w0 = tw[t * 2], w1 = tw[t * 2 + 1];
  float s0[4] = {0.f, 0.f, 0.f, 0.f}, s1[4] = {0.f, 0.f, 0.f, 0.f};
#pragma unroll
  for (int k = 0; k < 4; ++k) {
    const u16* yp = (k < 3) ? yp0 + (size_t)k * AK * HD : yp3;
    ushort4 v0 = *(const ushort4*)&yp[(size_t)a0 * HD + c];
    ushort4 v1 = *(const ushort4*)&yp[(size_t)a1 * HD + c];
    s0[0] += bf2f(v0.x); s0[1] += bf2f(v0.y); s0[2] += bf2f(v0.z); s0[3] += bf2f(v0.w);
    s1[0] += bf2f(v1.x); s1[1] += bf2f(v1.y); s1[2] += bf2f(v1.z); s1[3] += bf2f(v1.w);
  }
  float4 o;
  o.x = w0 * s0[0] + w1 * s1[0];
  o.y = w0 * s0[1] + w1 * s1[1];
  o.z = w0 * s0[2] + w1 * s1[2];
  o.w = w0 * s0[3] + w1 * s1[3];
  *(float4*)&out[(size_t)t * HD + c] = o;
}

// ---------------- host ----------------

extern "C" void kernel_launch(void* const* d_in, const int* in_sizes, int n_in,
                              void* d_out, int out_size, void* d_ws, size_t ws_size,
                              hipStream_t stream) {
  const float* x  = (const float*)d_in[0];
  const float* wg = (const float*)d_in[1];
  const float* w1 = (const float*)d_in[2];
  const float* w2 = (const float*)d_in[3];
  const float* w3 = (const float*)d_in[4];

  char* p = (char*)d_ws;
  auto alloc = [&](size_t bytes) {
    char* r = p;
    p += (bytes + 255) & ~(size_t)255;
    return r;
  };
  u16*   xb      = (u16*)alloc((size_t)T_TOK * HD * 2);           // 16 MiB
  u16*   w13b    = (u16*)alloc((size_t)NE * 2 * ID * HD * 2);     // 128 MiB [E][2I][H]
  u16*   w2b     = (u16*)alloc((size_t)NE * HD * ID * 2);         // 64 MiB  [E][H][I]
  u16*   hidden  = (u16*)alloc((size_t)APAD * ID * 2);            // 130 MiB
  u16*   yp3     = (u16*)alloc((size_t)AK * HD * 2);              // 34 MiB (4th partial)
  int*   tidx    = (int*)alloc(AK * 4);
  float* tw      = (float*)alloc(AK * 4);
  int*   list    = (int*)alloc(AK * 4);
  int*   pos     = (int*)alloc(AK * 4);
  int*   counts  = (int*)alloc(64);
  int*   offs    = (int*)alloc(64);
  int*   cursors = (int*)alloc(64);
  int*   tiles   = (int*)alloc(MTMAX * 4);
  int*   ntile   = (int*)alloc(64);
  (void)ws_size; (void)in_sizes; (void)n_in; (void)out_size;

  u16* yp0 = w13b;   // partials 0..2 alias w13b (dead after gemm1)

  k_init<<<1, 64, 0, stream>>>(counts);
  k_prepA<<<NBA_CVT + NBA_T13 + 2048, 256, 0, stream>>>(
      x, wg, w1, w3, xb, w13b, tidx, tw, counts);
  k_prepB<<<2048, 256, 0, stream>>>(w2, w2b);
  k_offsets<<<1, 64, 0, stream>>>(counts, offs, cursors, tiles, ntile);
  k_scatter<<<AK / 256, 256, 0, stream>>>(tidx, offs, cursors, list, pos);

  dim3 gg1(2 * ID / 256, MTMAX, 1);
  k_gemm1<<<gg1, 512, 0, stream>>>(xb, w13b, list, offs, tiles, ntile, hidden);
  dim3 gg2(16, MTMAX, 1);
  k_gemm2<<<gg2, 512, 0, stream>>>(hidden, w2b, offs, tiles, ntile, yp0, yp3);
  k_combine<<<T_TOK, 256, 0, stream>>>(yp0, yp3, pos, tw, (float*)d_out);
}

// Round 9
// 888.867 us; speedup vs baseline: 1.0304x; 1.0304x over previous
//
#include <hip/hip_runtime.h>

typedef unsigned short u16;
typedef __attribute__((ext_vector_type(4))) float f32x4;
typedef __attribute__((ext_vector_type(8))) short s16x8;

#define T_TOK 8192
#define HD    1024
#define ID    4096
#define NE    8
#define AK    (T_TOK * 2)      // total assignments (top-2)
#define APAD  (AK + 256)       // slack rows for 256-row A tiles
#define MTMAX 72               // max M-tiles: 16384/256 + 8 partials

#define BAR()   __builtin_amdgcn_s_barrier()
#define SB0()   __builtin_amdgcn_sched_barrier(0)
#define PRIO1() __builtin_amdgcn_s_setprio(1)
#define PRIO0() __builtin_amdgcn_s_setprio(0)
#define WAITV6() asm volatile("s_waitcnt vmcnt(6)" ::: "memory")
#define WAITV8() asm volatile("s_waitcnt vmcnt(8)" ::: "memory")
#define LGKM0()  do { asm volatile("s_waitcnt lgkmcnt(0)" ::: "memory"); SB0(); } while (0)

__device__ __forceinline__ u16 f2bf(float f) {
  unsigned u = __builtin_bit_cast(unsigned, f);
  u += 0x7FFFu + ((u >> 16) & 1u);   // round-to-nearest-even
  return (u16)(u >> 16);
}

__device__ __forceinline__ float bf2f(u16 v) {
  unsigned u = (unsigned)v << 16;
  return __builtin_bit_cast(float, u);
}

__device__ __forceinline__ void gld16(u16* lds, const u16* g) {
  __builtin_amdgcn_global_load_lds(
      (const __attribute__((address_space(1))) unsigned int*)g,
      (__attribute__((address_space(3))) unsigned int*)lds, 16, 0, 0);
}

// ---------------- routing helpers ----------------

__global__ void k_init(int* counts) {
  if (threadIdx.x < NE) counts[threadIdx.x] = 0;
}

__global__ void k_offsets(const int* __restrict__ counts, int* offs, int* cursors,
                          int* __restrict__ tiles, int* __restrict__ ntile) {
  if (threadIdx.x == 0) {
    int s = 0;
    for (int e = 0; e < NE; ++e) { offs[e] = s; s += counts[e]; }
    offs[NE] = s;
    int nt = 0;
    for (int e = 0; e < NE; ++e)
      for (int m0 = 0; m0 < counts[e]; m0 += 256)
        tiles[nt++] = (e << 16) | (m0 >> 8);
    ntile[0] = nt;
    for (int i = nt; i < MTMAX; ++i) tiles[i] = 0;
  }
  if (threadIdx.x < NE) cursors[threadIdx.x] = 0;
}

__global__ __launch_bounds__(256) void k_scatter(
    const int* __restrict__ tidx, const int* __restrict__ offs,
    int* cursors, int* __restrict__ list, int* __restrict__ pos) {
  int idx = blockIdx.x * 256 + threadIdx.x;
  if (idx >= AK) return;
  int e = tidx[idx];
  int p = atomicAdd(&cursors[e], 1);
  int a = offs[e] + p;
  list[a] = idx >> 1;
  pos[idx] = a;
}

// -------- transpose tile: in [R][C] fp32 -> out [C'][R] bf16 --------
// R-block 256, C-block 64. LDS [256][72] u16 row-major.
// Fill: ushort4 at tile[r][cc4] — lanes disjoint -> 0 conflicts.
// Drain: wave w owns rows [w*64, w*64+64), lane = column c; scalar reads at
// fixed r have bank = (r*36 + (c>>1)) % 32 -> 2 lanes/bank = free. Each
// thread emits 8 x 16B contiguous stores (128B run; 512B/row per block).

__device__ __forceinline__ void tconv_block(
    const float* __restrict__ in, u16* __restrict__ out,
    int R, int C, int r0, int c0, int which, int interleave, char* smem) {
  u16 (*tile)[72] = (u16(*)[72])smem;
  int t = threadIdx.x;
  int rr = t >> 4;            // 0..15
  int cc4 = (t & 15) * 4;
#pragma unroll
  for (int i = 0; i < 16; ++i) {
    int r = i * 16 + rr;      // 0..255
    float4 v = *(const float4*)&in[(size_t)(r0 + r) * C + c0 + cc4];
    ushort4 bv;
    bv.x = f2bf(v.x); bv.y = f2bf(v.y); bv.z = f2bf(v.z); bv.w = f2bf(v.w);
    *(ushort4*)&tile[r][cc4] = bv;
  }
  __syncthreads();
  int w = t >> 6;             // wave id 0..3 -> r-range
  int c = t & 63;             // column
  int gc = c0 + c;
  int orow = interleave ? (((gc >> 4) << 5) + which * 16 + (gc & 15)) : gc;
  u16* obase = out + (size_t)orow * R + r0 + w * 64;
#pragma unroll
  for (int j = 0; j < 8; ++j) {
    s16x8 o;
#pragma unroll
    for (int q = 0; q < 8; ++q) o[q] = (short)tile[w * 64 + j * 8 + q][c];
    *(s16x8*)&obase[j * 8] = o;
  }
}

// ---------------- fused prep: cvtx + w13 + w2 + router (one grid) ----------------
#define NBP_CVT 4096
#define NBP_T13 4096    // 2E(16) x H/256(4) x I/64(64)
#define NBP_T2  2048    // E(8) x I/256(16) x H/64(16)
#define NBP_RTR 2048

__global__ __launch_bounds__(256) void k_prep(
    const float* __restrict__ x, const float* __restrict__ wg,
    const float* __restrict__ w1, const float* __restrict__ w2,
    const float* __restrict__ w3,
    u16* __restrict__ xb, u16* __restrict__ w13b, u16* __restrict__ w2b,
    int* __restrict__ tidx, float* __restrict__ tw, int* __restrict__ counts) {
  __shared__ char smem[256 * 72 * 2];        // 36 KB (router uses 32 KB)
  int bid = blockIdx.x, t = threadIdx.x;

  if (bid < NBP_CVT) {                       // ---- cvtx: 8 floats/thread
    int idx = bid * 256 + t;
    float4 v0 = ((const float4*)x)[idx * 2];
    float4 v1 = ((const float4*)x)[idx * 2 + 1];
    s16x8 o;
    o[0] = (short)f2bf(v0.x); o[1] = (short)f2bf(v0.y);
    o[2] = (short)f2bf(v0.z); o[3] = (short)f2bf(v0.w);
    o[4] = (short)f2bf(v1.x); o[5] = (short)f2bf(v1.y);
    o[6] = (short)f2bf(v1.z); o[7] = (short)f2bf(v1.w);
    ((s16x8*)xb)[idx] = o;
    return;
  }
  if (bid < NBP_CVT + NBP_T13) {             // ---- w1/w3 [H][I] -> w13b [2I][H]
    int r = bid - NBP_CVT;
    int bx = r & 63;                         // I/64
    int by = (r >> 6) & 3;                   // H/256
    int bz = r >> 8;                         // 0..15 = 2E
    int which = bz >> 3, e = bz & 7;
    const float* in = (which ? w3 : w1) + (size_t)e * HD * ID;
    tconv_block(in, w13b + (size_t)e * 2 * ID * HD,
                HD, ID, by * 256, bx * 64, which, 1, smem);
    return;
  }
  if (bid < NBP_CVT + NBP_T13 + NBP_T2) {    // ---- w2 [I][H] -> w2b [H][I]
    int r = bid - NBP_CVT - NBP_T13;
    int bx = r & 15;                         // H/64
    int by = (r >> 4) & 15;                  // I/256
    int e = r >> 8;
    tconv_block(w2 + (size_t)e * ID * HD, w2b + (size_t)e * HD * ID,
                ID, HD, by * 256, bx * 64, 0, 0, smem);
    return;
  }
  {                                          // ---- router
    float* wgs = (float*)smem;               // [e][h] transposed, 32 KB
    int blockR = bid - NBP_CVT - NBP_T13 - NBP_T2;
    for (int i = t; i < NE * HD; i += 256) {
      int h = i >> 3, e = i & 7;
      wgs[e * HD + h] = wg[i];
    }
    __syncthreads();
    int lane = t & 63, wid = t >> 6;
    int tok = blockR * 4 + wid;
    const float* xr = x + (size_t)tok * HD;
    double acc[NE];
#pragma unroll
    for (int e = 0; e < NE; ++e) acc[e] = 0.0;
    for (int i = 0; i < HD / 64; ++i) {
      float xv = xr[lane + i * 64];
#pragma unroll
      for (int e = 0; e < NE; ++e)
        acc[e] += (double)xv * (double)wgs[e * HD + lane + i * 64];
    }
#pragma unroll
    for (int e = 0; e < NE; ++e)
      for (int s = 32; s >= 1; s >>= 1) acc[e] += __shfl_xor(acc[e], s, 64);
    int e0 = 0; double m0 = acc[0];
    for (int e = 1; e < NE; ++e) if (acc[e] > m0) { m0 = acc[e]; e0 = e; }
    int e1 = -1; double m1 = -1e300;
    for (int e = 0; e < NE; ++e) if (e != e0 && acc[e] > m1) { m1 = acc[e]; e1 = e; }
    if (lane == 0) {
      double d = exp(m1 - m0);
      tidx[tok * 2] = e0; tidx[tok * 2 + 1] = e1;
      tw[tok * 2] = (float)(1.0 / (1.0 + d));
      tw[tok * 2 + 1] = (float)(d / (1.0 + d));
      atomicAdd(&counts[e0], 1);
      atomicAdd(&counts[e1], 1);
    }
  }
}

// ============ 8-phase GEMM core (256x256x64, 8 waves 2Mx4N) ============

#define GEMM_CORE(NTK, NITER) \
  int wr = wid >> 2, wc = wid & 3; \
  int lane15 = lane & 15, lq = lane >> 4, sw8 = lane15 & 7; \
  f32x4 acc[8][4]; \
  _Pragma("unroll") for (int m = 0; m < 8; ++m) \
    _Pragma("unroll") for (int n = 0; n < 4; ++n) acc[m][n] = (f32x4){0.f,0.f,0.f,0.f}; \
  auto stgA = [&](int bb, int h, int kt) { \
    gld16(&As[bb][(h*128 + 0*64 + wid*8) * 64], gA[h*2+0] + kt*64); \
    gld16(&As[bb][(h*128 + 1*64 + wid*8) * 64], gA[h*2+1] + kt*64); }; \
  auto stgB = [&](int bb, int h, int kt) { \
    gld16(&Bs[bb][(h*128 + 0*64 + wid*8) * 64], gB[h*2+0] + kt*64); \
    gld16(&Bs[bb][(h*128 + 1*64 + wid*8) * 64], gB[h*2+1] + kt*64); }; \
  s16x8 a[4][2], b[4][2]; \
  auto rdA = [&](int bb, int mh) { \
    _Pragma("unroll") for (int mm = 0; mm < 4; ++mm) \
      _Pragma("unroll") for (int kk = 0; kk < 2; ++kk) \
        a[mm][kk] = *(const s16x8*)&As[bb][(mh*128 + wr*64 + mm*16 + lane15)*64 + (((kk*4+lq)^sw8)*8)]; }; \
  auto rdB = [&](int bb, int fh) { \
    _Pragma("unroll") for (int ff = 0; ff < 2; ++ff) \
      _Pragma("unroll") for (int kk = 0; kk < 2; ++kk) \
        b[fh*2+ff][kk] = *(const s16x8*)&Bs[bb][(fh*128 + wc*32 + ff*16 + lane15)*64 + (((kk*4+lq)^sw8)*8)]; }; \
  auto mf = [&](int mh, int fh) { \
    _Pragma("unroll") for (int kk = 0; kk < 2; ++kk) \
      _Pragma("unroll") for (int mm = 0; mm < 4; ++mm) \
        _Pragma("unroll") for (int ff = 0; ff < 2; ++ff) \
          acc[mh*4+mm][fh*2+ff] = __builtin_amdgcn_mfma_f32_16x16x32_bf16(a[mm][kk], b[fh*2+ff][kk], acc[mh*4+mm][fh*2+ff], 0, 0, 0); }; \
  /* prologue */ \
  stgA(0,0,0); stgB(0,0,0); stgA(0,1,0); stgB(0,1,0); stgA(1,0,1); stgB(1,0,1); \
  WAITV8(); BAR(); SB0(); \
  for (int i = 0; i < (NITER); ++i) { \
    int ku2 = (2*i+2) & ((NTK)-1), ku3 = (2*i+3) & ((NTK)-1); \
    /* p1 */ rdA(0,0); rdB(0,0); stgA(1,1,2*i+1); WAITV6(); BAR(); LGKM0(); PRIO1(); mf(0,0); PRIO0(); BAR(); SB0(); \
    /* p2 */ rdB(0,1); stgB(1,1,2*i+1); BAR(); LGKM0(); PRIO1(); mf(0,1); PRIO0(); BAR(); SB0(); \
    /* p3 */ rdA(0,1); stgA(0,0,ku2); BAR(); LGKM0(); PRIO1(); mf(1,0); PRIO0(); BAR(); SB0(); \
    /* p4 */ stgB(0,0,ku2); WAITV8(); BAR(); PRIO1(); mf(1,1); PRIO0(); BAR(); SB0(); \
    /* p5 */ rdA(1,0); rdB(1,0); stgA(0,1,ku2); WAITV6(); BAR(); LGKM0(); PRIO1(); mf(0,0); PRIO0(); BAR(); SB0(); \
    /* p6 */ rdB(1,1); stgB(0,1,ku2); BAR(); LGKM0(); PRIO1(); mf(0,1); PRIO0(); BAR(); SB0(); \
    /* p7 */ rdA(1,1); stgA(1,0,ku3); BAR(); LGKM0(); PRIO1(); mf(1,0); PRIO0(); BAR(); SB0(); \
    /* p8 */ stgB(1,0,ku3); WAITV8(); BAR(); PRIO1(); mf(1,1); PRIO0(); BAR(); SB0(); \
  }

// ---- GEMM1: hidden = silu(x@w1)*(x@w3); B = interleaved w13; gathered A ----
__global__ __launch_bounds__(512, 1) void k_gemm1(
    const u16* __restrict__ xb, const u16* __restrict__ w13b,
    const int* __restrict__ list, const int* __restrict__ offs,
    const int* __restrict__ tiles, const int* __restrict__ ntile,
    u16* __restrict__ hidden) {
  int ti = blockIdx.y;
  if (ti >= ntile[0]) return;
  int packed = tiles[ti];
  int e = packed >> 16;
  int m0 = (packed & 0xFFFF) << 8;
  int aoff = offs[e];
  int cnt = offs[e + 1] - aoff;
  int n0 = blockIdx.x * 256;          // over 2I interleaved

  __shared__ u16 As[2][256 * 64];
  __shared__ u16 Bs[2][256 * 64];

  int tid = threadIdx.x, lane = tid & 63, wid = tid >> 6;
  int l8 = lane >> 3, c8 = lane & 7;
  int csrc = (c8 ^ l8) * 8;

  const u16* gA[4]; const u16* gB[4];
#pragma unroll
  for (int h = 0; h < 2; ++h)
#pragma unroll
    for (int c = 0; c < 2; ++c) {
      int row = h * 128 + c * 64 + wid * 8 + l8;
      int rr = m0 + row; if (rr > cnt - 1) rr = cnt - 1;
      gA[h*2+c] = xb + (size_t)list[aoff + rr] * HD + csrc;
      gB[h*2+c] = w13b + ((size_t)e * 2 * ID + n0 + row) * HD + csrc;
    }

  GEMM_CORE(HD / 64, HD / 128)

#pragma unroll
  for (int mh = 0; mh < 2; ++mh)
#pragma unroll
    for (int mm = 0; mm < 4; ++mm)
#pragma unroll
      for (int j = 0; j < 4; ++j) {
        int grow = m0 + mh * 128 + wr * 64 + mm * 16 + lq * 4 + j;
        if (grow < cnt) {
          size_t rbase = (size_t)(aoff + grow) * ID;
#pragma unroll
          for (int p = 0; p < 2; ++p) {
            float v1 = acc[mh*4+mm][2*p][j];
            float v3 = acc[mh*4+mm][2*p+1][j];
            float s = v1 / (1.0f + __expf(-v1));
            int icol = ((n0 + p * 128 + wc * 32) >> 1) + lane15;
            hidden[rbase + icol] = f2bf(s * v3);
          }
        }
      }
}

// ---- GEMM2: yp[kchunk][a] = hidden_chunk @ w2_chunk (bf16 partials) ----
__global__ __launch_bounds__(512, 1) void k_gemm2(
    const u16* __restrict__ hidden, const u16* __restrict__ w2b,
    const int* __restrict__ offs, const int* __restrict__ tiles,
    const int* __restrict__ ntile,
    u16* __restrict__ yp0, u16* __restrict__ yp3) {
  int ti = blockIdx.y;
  if (ti >= ntile[0]) return;
  int packed = tiles[ti];
  int e = packed >> 16;
  int m0 = (packed & 0xFFFF) << 8;
  int aoff = offs[e];
  int cnt = offs[e + 1] - aoff;
  int n0 = (blockIdx.x & 3) * 256;    // H cols
  int kidx = blockIdx.x >> 2;
  int kc = kidx * 1024;               // K chunk base (elements)

  __shared__ u16 As[2][256 * 64];
  __shared__ u16 Bs[2][256 * 64];

  int tid = threadIdx.x, lane = tid & 63, wid = tid >> 6;
  int l8 = lane >> 3, c8 = lane & 7;
  int csrc = (c8 ^ l8) * 8;

  const u16* gA[4]; const u16* gB[4];
#pragma unroll
  for (int h = 0; h < 2; ++h)
#pragma unroll
    for (int c = 0; c < 2; ++c) {
      int row = h * 128 + c * 64 + wid * 8 + l8;
      gA[h*2+c] = hidden + (size_t)(aoff + m0 + row) * ID + kc + csrc;  // APAD slack
      gB[h*2+c] = w2b + ((size_t)e * HD + n0 + row) * ID + kc + csrc;
    }

  GEMM_CORE(1024 / 64, 1024 / 128)

  u16* yp = (kidx < 3) ? yp0 + (size_t)kidx * AK * HD : yp3;
#pragma unroll
  for (int mh = 0; mh < 2; ++mh)
#pragma unroll
    for (int mm = 0; mm < 4; ++mm)
#pragma unroll
      for (int j = 0; j < 4; ++j) {
        int grow = m0 + mh * 128 + wr * 64 + mm * 16 + lq * 4 + j;
        if (grow < cnt) {
          u16* yrow = yp + (size_t)(aoff + grow) * HD;
#pragma unroll
          for (int f = 0; f < 4; ++f) {
            int col = n0 + (f >> 1) * 128 + wc * 32 + (f & 1) * 16 + lane15;
            yrow[col] = f2bf(acc[mh*4+mm][f][j]);
          }
        }
      }
}

// ---- combine: out[t] = w0*sum_k yp[k][p0] + w1*sum_k yp[k][p1] ----
__global__ __launch_bounds__(256) void k_combine(
    const u16* __restrict__ yp0, const u16* __restrict__ yp3,
    const int* __restrict__ pos, const float* __restrict__ tw,
    float* __restrict__ out) {
  int t = blockIdx.x;
  int c = threadIdx.x * 4;
  int a0 = pos[t * 2], a1 = pos[t * 2 + 1];
  float w0 = tw[t * 2], w1 = tw[t * 2 + 1];
  float s0[4] = {0.f, 0.f, 0.f, 0.f}, s1[4] = {0.f, 0.f, 0.f, 0.f};
#pragma unroll
  for (int k = 0; k < 4; ++k) {
    const u16* yp = (k < 3) ? yp0 + (size_t)k * AK * HD : yp3;
    ushort4 v0 = *(const ushort4*)&yp[(size_t)a0 * HD + c];
    ushort4 v1 = *(const ushort4*)&yp[(size_t)a1 * HD + c];
    s0[0] += bf2f(v0.x); s0[1] += bf2f(v0.y); s0[2] += bf2f(v0.z); s0[3] += bf2f(v0.w);
    s1[0] += bf2f(v1.x); s1[1] += bf2f(v1.y); s1[2] += bf2f(v1.z); s1[3] += bf2f(v1.w);
  }
  float4 o;
  o.x = w0 * s0[0] + w1 * s1[0];
  o.y = w0 * s0[1] + w1 * s1[1];
  o.z = w0 * s0[2] + w1 * s1[2];
  o.w = w0 * s0[3] + w1 * s1[3];
  *(float4*)&out[(size_t)t * HD + c] = o;
}

// ---------------- host ----------------

extern "C" void kernel_launch(void* const* d_in, const int* in_sizes, int n_in,
                              void* d_out, int out_size, void* d_ws, size_t ws_size,
                              hipStream_t stream) {
  const float* x  = (const float*)d_in[0];
  const float* wg = (const float*)d_in[1];
  const float* w1 = (const float*)d_in[2];
  const float* w2 = (const float*)d_in[3];
  const float* w3 = (const float*)d_in[4];

  char* p = (char*)d_ws;
  auto alloc = [&](size_t bytes) {
    char* r = p;
    p += (bytes + 255) & ~(size_t)255;
    return r;
  };
  u16*   xb      = (u16*)alloc((size_t)T_TOK * HD * 2);           // 16 MiB
  u16*   w13b    = (u16*)alloc((size_t)NE * 2 * ID * HD * 2);     // 128 MiB [E][2I][H]
  u16*   w2b     = (u16*)alloc((size_t)NE * HD * ID * 2);         // 64 MiB  [E][H][I]
  u16*   hidden  = (u16*)alloc((size_t)APAD * ID * 2);            // 130 MiB
  u16*   yp3     = (u16*)alloc((size_t)AK * HD * 2);              // 34 MiB (4th partial)
  int*   tidx    = (int*)alloc(AK * 4);
  float* tw      = (float*)alloc(AK * 4);
  int*   list    = (int*)alloc(AK * 4);
  int*   pos     = (int*)alloc(AK * 4);
  int*   counts  = (int*)alloc(64);
  int*   offs    = (int*)alloc(64);
  int*   cursors = (int*)alloc(64);
  int*   tiles   = (int*)alloc(MTMAX * 4);
  int*   ntile   = (int*)alloc(64);
  (void)ws_size; (void)in_sizes; (void)n_in; (void)out_size;

  u16* yp0 = w13b;   // partials 0..2 alias w13b (dead after gemm1)

  k_init<<<1, 64, 0, stream>>>(counts);
  k_prep<<<NBP_CVT + NBP_T13 + NBP_T2 + NBP_RTR, 256, 0, stream>>>(
      x, wg, w1, w2, w3, xb, w13b, w2b, tidx, tw, counts);
  k_offsets<<<1, 64, 0, stream>>>(counts, offs, cursors, tiles, ntile);
  k_scatter<<<AK / 256, 256, 0, stream>>>(tidx, offs, cursors, list, pos);

  dim3 gg1(2 * ID / 256, MTMAX, 1);
  k_gemm1<<<gg1, 512, 0, stream>>>(xb, w13b, list, offs, tiles, ntile, hidden);
  dim3 gg2(16, MTMAX, 1);
  k_gemm2<<<gg2, 512, 0, stream>>>(hidden, w2b, offs, tiles, ntile, yp0, yp3);
  k_combine<<<T_TOK, 256, 0, stream>>>(yp0, yp3, pos, tw, (float*)d_out);
}

// Round 10
// 870.040 us; speedup vs baseline: 1.0527x; 1.0216x over previous
//
#include <hip/hip_runtime.h>

typedef unsigned short u16;
typedef __attribute__((ext_vector_type(4))) float f32x4;
typedef __attribute__((ext_vector_type(8))) short s16x8;

#define T_TOK 8192
#define HD    1024
#define ID    4096
#define NE    8
#define AK    (T_TOK * 2)      // total assignments (top-2)
#define APAD  (AK + 256)       // slack rows for 256-row A tiles
#define MTMAX 72               // max M-tiles: 16384/256 + 8 partials

#define BAR()   __builtin_amdgcn_s_barrier()
#define SB0()   __builtin_amdgcn_sched_barrier(0)
#define PRIO1() __builtin_amdgcn_s_setprio(1)
#define PRIO0() __builtin_amdgcn_s_setprio(0)
#define WAITV6() asm volatile("s_waitcnt vmcnt(6)" ::: "memory")
#define WAITV8() asm volatile("s_waitcnt vmcnt(8)" ::: "memory")
#define LGKM0()  do { asm volatile("s_waitcnt lgkmcnt(0)" ::: "memory"); SB0(); } while (0)

__device__ __forceinline__ u16 f2bf(float f) {
  unsigned u = __builtin_bit_cast(unsigned, f);
  u += 0x7FFFu + ((u >> 16) & 1u);   // round-to-nearest-even
  return (u16)(u >> 16);
}

__device__ __forceinline__ float bf2f(u16 v) {
  unsigned u = (unsigned)v << 16;
  return __builtin_bit_cast(float, u);
}

__device__ __forceinline__ void gld16(u16* lds, const u16* g) {
  __builtin_amdgcn_global_load_lds(
      (const __attribute__((address_space(1))) unsigned int*)g,
      (__attribute__((address_space(3))) unsigned int*)lds, 16, 0, 0);
}

// ---------------- routing helpers ----------------

__global__ void k_init(int* counts) {
  if (threadIdx.x < NE) counts[threadIdx.x] = 0;
}

__global__ void k_offsets(const int* __restrict__ counts, int* offs, int* cursors,
                          int* __restrict__ tiles, int* __restrict__ ntile) {
  if (threadIdx.x == 0) {
    int s = 0;
    for (int e = 0; e < NE; ++e) { offs[e] = s; s += counts[e]; }
    offs[NE] = s;
    int nt = 0;
    for (int e = 0; e < NE; ++e)
      for (int m0 = 0; m0 < counts[e]; m0 += 256)
        tiles[nt++] = (e << 16) | (m0 >> 8);
    ntile[0] = nt;
    for (int i = nt; i < MTMAX; ++i) tiles[i] = 0;
  }
  if (threadIdx.x < NE) cursors[threadIdx.x] = 0;
}

__global__ __launch_bounds__(256) void k_scatter(
    const int* __restrict__ tidx, const int* __restrict__ offs,
    int* cursors, int* __restrict__ list, int* __restrict__ pos) {
  int idx = blockIdx.x * 256 + threadIdx.x;
  if (idx >= AK) return;
  int e = tidx[idx];
  int p = atomicAdd(&cursors[e], 1);
  int a = offs[e] + p;
  list[a] = idx >> 1;
  pos[idx] = a;
}

// ---------------- prep: w13 transpose + router(+xb) in one grid ----------------
// w13 transpose: in [R][C] fp32 -> out [C'][R] bf16, 256x64 tile, LDS [256][72].
// Fill ushort4 (disjoint -> 0 conflicts); drain scalar at fixed r (2-way free),
// 8x16B contiguous stores.

#define NBP_T13 4096    // 2E(16) x H/256(4) x I/64(64)
#define NBP_RTR 2048

__global__ __launch_bounds__(256) void k_prep(
    const float* __restrict__ x, const float* __restrict__ wg,
    const float* __restrict__ w1, const float* __restrict__ w3,
    u16* __restrict__ xb, u16* __restrict__ w13b,
    int* __restrict__ tidx, float* __restrict__ tw, int* __restrict__ counts) {
  __shared__ char smem[256 * 72 * 2];        // 36 KB (router uses 32 KB)
  int bid = blockIdx.x, t = threadIdx.x;

  if (bid < NBP_T13) {                       // ---- w1/w3 [H][I] -> w13b [2I][H]
    u16 (*tile)[72] = (u16(*)[72])smem;
    int bx = bid & 63;                       // I/64
    int by = (bid >> 6) & 3;                 // H/256
    int bz = bid >> 8;                       // 0..15 = 2E
    int which = bz >> 3, e = bz & 7;
    const float* in = (which ? w3 : w1) + (size_t)e * HD * ID;
    int r0 = by * 256, c0 = bx * 64;
    int rr = t >> 4, cc4 = (t & 15) * 4;
#pragma unroll
    for (int i = 0; i < 16; ++i) {
      int r = i * 16 + rr;
      float4 v = *(const float4*)&in[(size_t)(r0 + r) * ID + c0 + cc4];
      ushort4 bv;
      bv.x = f2bf(v.x); bv.y = f2bf(v.y); bv.z = f2bf(v.z); bv.w = f2bf(v.w);
      *(ushort4*)&tile[r][cc4] = bv;
    }
    __syncthreads();
    int w = t >> 6, c = t & 63;
    int gc = c0 + c;
    int orow = ((gc >> 4) << 5) + which * 16 + (gc & 15);
    u16* obase = w13b + ((size_t)e * 2 * ID + orow) * HD + r0 + w * 64;
#pragma unroll
    for (int j = 0; j < 8; ++j) {
      s16x8 o;
#pragma unroll
      for (int q = 0; q < 8; ++q) o[q] = (short)tile[w * 64 + j * 8 + q][c];
      *(s16x8*)&obase[j * 8] = o;
    }
    return;
  }
  {                                          // ---- router + xb emit
    float* wgs = (float*)smem;               // [e][h] transposed, 32 KB
    int blockR = bid - NBP_T13;
    for (int i = t; i < NE * HD; i += 256) {
      int h = i >> 3, e = i & 7;
      wgs[e * HD + h] = wg[i];
    }
    __syncthreads();
    int lane = t & 63, wid = t >> 6;
    int tok = blockR * 4 + wid;
    const float* xr = x + (size_t)tok * HD;
    u16* xo = xb + (size_t)tok * HD;
    double acc[NE];
#pragma unroll
    for (int e = 0; e < NE; ++e) acc[e] = 0.0;
    for (int i = 0; i < HD / 64; ++i) {
      float xv = xr[lane + i * 64];
      xo[lane + i * 64] = f2bf(xv);
#pragma unroll
      for (int e = 0; e < NE; ++e)
        acc[e] += (double)xv * (double)wgs[e * HD + lane + i * 64];
    }
#pragma unroll
    for (int e = 0; e < NE; ++e)
      for (int s = 32; s >= 1; s >>= 1) acc[e] += __shfl_xor(acc[e], s, 64);
    int e0 = 0; double m0 = acc[0];
    for (int e = 1; e < NE; ++e) if (acc[e] > m0) { m0 = acc[e]; e0 = e; }
    int e1 = -1; double m1 = -1e300;
    for (int e = 0; e < NE; ++e) if (e != e0 && acc[e] > m1) { m1 = acc[e]; e1 = e; }
    if (lane == 0) {
      double d = exp(m1 - m0);
      tidx[tok * 2] = e0; tidx[tok * 2 + 1] = e1;
      tw[tok * 2] = (float)(1.0 / (1.0 + d));
      tw[tok * 2 + 1] = (float)(d / (1.0 + d));
      atomicAdd(&counts[e0], 1);
      atomicAdd(&counts[e1], 1);
    }
  }
}

// ============ 8-phase GEMM core (256x256x64, 8 waves 2Mx4N) ============

#define GEMM_CORE(NTK, NITER) \
  int wr = wid >> 2, wc = wid & 3; \
  int lane15 = lane & 15, lq = lane >> 4, sw8 = lane15 & 7; \
  f32x4 acc[8][4]; \
  _Pragma("unroll") for (int m = 0; m < 8; ++m) \
    _Pragma("unroll") for (int n = 0; n < 4; ++n) acc[m][n] = (f32x4){0.f,0.f,0.f,0.f}; \
  auto stgA = [&](int bb, int h, int kt) { \
    gld16(&As[bb][(h*128 + 0*64 + wid*8) * 64], gA[h*2+0] + kt*64); \
    gld16(&As[bb][(h*128 + 1*64 + wid*8) * 64], gA[h*2+1] + kt*64); }; \
  auto stgB = [&](int bb, int h, int kt) { \
    gld16(&Bs[bb][(h*128 + 0*64 + wid*8) * 64], gB[h*2+0] + kt*64); \
    gld16(&Bs[bb][(h*128 + 1*64 + wid*8) * 64], gB[h*2+1] + kt*64); }; \
  s16x8 a[4][2], b[4][2]; \
  auto rdA = [&](int bb, int mh) { \
    _Pragma("unroll") for (int mm = 0; mm < 4; ++mm) \
      _Pragma("unroll") for (int kk = 0; kk < 2; ++kk) \
        a[mm][kk] = *(const s16x8*)&As[bb][(mh*128 + wr*64 + mm*16 + lane15)*64 + (((kk*4+lq)^sw8)*8)]; }; \
  auto rdB = [&](int bb, int fh) { \
    _Pragma("unroll") for (int ff = 0; ff < 2; ++ff) \
      _Pragma("unroll") for (int kk = 0; kk < 2; ++kk) \
        b[fh*2+ff][kk] = *(const s16x8*)&Bs[bb][(fh*128 + wc*32 + ff*16 + lane15)*64 + (((kk*4+lq)^sw8)*8)]; }; \
  auto mf = [&](int mh, int fh) { \
    _Pragma("unroll") for (int kk = 0; kk < 2; ++kk) \
      _Pragma("unroll") for (int mm = 0; mm < 4; ++mm) \
        _Pragma("unroll") for (int ff = 0; ff < 2; ++ff) \
          acc[mh*4+mm][fh*2+ff] = __builtin_amdgcn_mfma_f32_16x16x32_bf16(a[mm][kk], b[fh*2+ff][kk], acc[mh*4+mm][fh*2+ff], 0, 0, 0); }; \
  /* prologue */ \
  stgA(0,0,0); stgB(0,0,0); stgA(0,1,0); stgB(0,1,0); stgA(1,0,1); stgB(1,0,1); \
  WAITV8(); BAR(); SB0(); \
  for (int i = 0; i < (NITER); ++i) { \
    int ku2 = (2*i+2) & ((NTK)-1), ku3 = (2*i+3) & ((NTK)-1); \
    /* p1 */ rdA(0,0); rdB(0,0); stgA(1,1,2*i+1); WAITV6(); BAR(); LGKM0(); PRIO1(); mf(0,0); PRIO0(); BAR(); SB0(); \
    /* p2 */ rdB(0,1); stgB(1,1,2*i+1); BAR(); LGKM0(); PRIO1(); mf(0,1); PRIO0(); BAR(); SB0(); \
    /* p3 */ rdA(0,1); stgA(0,0,ku2); BAR(); LGKM0(); PRIO1(); mf(1,0); PRIO0(); BAR(); SB0(); \
    /* p4 */ stgB(0,0,ku2); WAITV8(); BAR(); PRIO1(); mf(1,1); PRIO0(); BAR(); SB0(); \
    /* p5 */ rdA(1,0); rdB(1,0); stgA(0,1,ku2); WAITV6(); BAR(); LGKM0(); PRIO1(); mf(0,0); PRIO0(); BAR(); SB0(); \
    /* p6 */ rdB(1,1); stgB(0,1,ku2); BAR(); LGKM0(); PRIO1(); mf(0,1); PRIO0(); BAR(); SB0(); \
    /* p7 */ rdA(1,1); stgA(1,0,ku3); BAR(); LGKM0(); PRIO1(); mf(1,0); PRIO0(); BAR(); SB0(); \
    /* p8 */ stgB(1,0,ku3); WAITV8(); BAR(); PRIO1(); mf(1,1); PRIO0(); BAR(); SB0(); \
  }

// ---- GEMM1 + tail-fused w2 transpose ----
// y < MTMAX: hidden = silu(x@w1)*(x@w3).  y >= MTMAX: w2 [I][H]->[H][I] tile
// (dispatched last -> fills the 224 idle CUs during gemm1's final round).

__global__ __launch_bounds__(512, 1) void k_gemm1(
    const u16* __restrict__ xb, const u16* __restrict__ w13b,
    const int* __restrict__ list, const int* __restrict__ offs,
    const int* __restrict__ tiles, const int* __restrict__ ntile,
    u16* __restrict__ hidden,
    const float* __restrict__ w2, u16* __restrict__ w2b) {
  __shared__ u16 As[2][256 * 64];
  __shared__ u16 Bs[2][256 * 64];
  int tid = threadIdx.x, lane = tid & 63, wid = tid >> 6;

  if (blockIdx.y >= MTMAX) {                 // ---- w2 transpose (512 thr)
    u16 (*tile)[64] = (u16(*)[64])&As[0][0]; // 32 KB region
    int flat = (blockIdx.y - MTMAX) * 32 + blockIdx.x;   // 0..2047
    int bx = flat & 15, by = (flat >> 4) & 15, e2 = flat >> 8;
    const float* in = w2 + (size_t)e2 * ID * HD;
    u16* outp = w2b + (size_t)e2 * HD * ID;
    int r0 = by * 256, c0 = bx * 64;
    int rr = tid >> 4, cc4 = (tid & 15) * 4;
#pragma unroll
    for (int i = 0; i < 8; ++i) {
      int r = i * 32 + rr;
      float4 v = *(const float4*)&in[(size_t)(r0 + r) * HD + c0 + cc4];
      ushort4 bv;
      bv.x = f2bf(v.x); bv.y = f2bf(v.y); bv.z = f2bf(v.z); bv.w = f2bf(v.w);
      *(ushort4*)&tile[r][cc4] = bv;
    }
    __syncthreads();
    int w = tid >> 6, c = tid & 63;
    u16* obase = outp + (size_t)(c0 + c) * ID + r0 + w * 32;
#pragma unroll
    for (int j = 0; j < 4; ++j) {
      s16x8 o;
#pragma unroll
      for (int q = 0; q < 8; ++q) o[q] = (short)tile[w * 32 + j * 8 + q][c];
      *(s16x8*)&obase[j * 8] = o;
    }
    return;
  }

  int ti = blockIdx.y;
  if (ti >= ntile[0]) return;
  int packed = tiles[ti];
  int e = packed >> 16;
  int m0 = (packed & 0xFFFF) << 8;
  int aoff = offs[e];
  int cnt = offs[e + 1] - aoff;
  int n0 = blockIdx.x * 256;          // over 2I interleaved

  int l8 = lane >> 3, c8 = lane & 7;
  int csrc = (c8 ^ l8) * 8;

  const u16* gA[4]; const u16* gB[4];
#pragma unroll
  for (int h = 0; h < 2; ++h)
#pragma unroll
    for (int c = 0; c < 2; ++c) {
      int row = h * 128 + c * 64 + wid * 8 + l8;
      int rr = m0 + row; if (rr > cnt - 1) rr = cnt - 1;
      gA[h*2+c] = xb + (size_t)list[aoff + rr] * HD + csrc;
      gB[h*2+c] = w13b + ((size_t)e * 2 * ID + n0 + row) * HD + csrc;
    }

  GEMM_CORE(HD / 64, HD / 128)

  // epilogue: SwiGLU -> LDS restage -> 16B stores (256B runs)
  u16 (*Ls)[132] = (u16(*)[132])&As[0][0];   // 67.6 KB, reuses K-loop LDS
  BAR();
#pragma unroll
  for (int mh = 0; mh < 2; ++mh)
#pragma unroll
    for (int mm = 0; mm < 4; ++mm)
#pragma unroll
      for (int j = 0; j < 4; ++j) {
        int rl = mh * 128 + wr * 64 + mm * 16 + lq * 4 + j;
#pragma unroll
        for (int p = 0; p < 2; ++p) {
          float v1 = acc[mh*4+mm][2*p][j];
          float v3 = acc[mh*4+mm][2*p+1][j];
          float s = v1 / (1.0f + __expf(-v1));
          Ls[rl][p * 64 + wc * 16 + lane15] = f2bf(s * v3);
        }
      }
  BAR();
#pragma unroll
  for (int ps = 0; ps < 8; ++ps) {
    int r = ps * 32 + (tid >> 4);
    int grow = m0 + r;
    if (grow < cnt) {
      int cl = (tid & 15) * 8;
      *(s16x8*)&hidden[(size_t)(aoff + grow) * ID + (n0 >> 1) + cl] =
          *(const s16x8*)&Ls[r][cl];
    }
  }
}

// ---- GEMM2: yp[kchunk][a] = hidden_chunk @ w2_chunk (bf16 partials) ----
__global__ __launch_bounds__(512, 1) void k_gemm2(
    const u16* __restrict__ hidden, const u16* __restrict__ w2b,
    const int* __restrict__ offs, const int* __restrict__ tiles,
    const int* __restrict__ ntile,
    u16* __restrict__ yp0, u16* __restrict__ yp3) {
  int ti = blockIdx.y;
  if (ti >= ntile[0]) return;
  int packed = tiles[ti];
  int e = packed >> 16;
  int m0 = (packed & 0xFFFF) << 8;
  int aoff = offs[e];
  int cnt = offs[e + 1] - aoff;
  int n0 = (blockIdx.x & 3) * 256;    // H cols
  int kidx = blockIdx.x >> 2;
  int kc = kidx * 1024;               // K chunk base (elements)

  __shared__ u16 As[2][256 * 64];
  __shared__ u16 Bs[2][256 * 64];

  int tid = threadIdx.x, lane = tid & 63, wid = tid >> 6;
  int l8 = lane >> 3, c8 = lane & 7;
  int csrc = (c8 ^ l8) * 8;

  const u16* gA[4]; const u16* gB[4];
#pragma unroll
  for (int h = 0; h < 2; ++h)
#pragma unroll
    for (int c = 0; c < 2; ++c) {
      int row = h * 128 + c * 64 + wid * 8 + l8;
      gA[h*2+c] = hidden + (size_t)(aoff + m0 + row) * ID + kc + csrc;  // APAD slack
      gB[h*2+c] = w2b + ((size_t)e * HD + n0 + row) * ID + kc + csrc;
    }

  GEMM_CORE(1024 / 64, 1024 / 128)

  u16* yp = (kidx < 3) ? yp0 + (size_t)kidx * AK * HD : yp3;
  u16 (*Ls)[132] = (u16(*)[132])&As[0][0];
#pragma unroll
  for (int half = 0; half < 2; ++half) {
    BAR();
#pragma unroll
    for (int mh = 0; mh < 2; ++mh)
#pragma unroll
      for (int mm = 0; mm < 4; ++mm)
#pragma unroll
        for (int j = 0; j < 4; ++j) {
          int rl = mh * 128 + wr * 64 + mm * 16 + lq * 4 + j;
#pragma unroll
          for (int fo = 0; fo < 2; ++fo) {
            int f = half * 2 + fo;
            Ls[rl][wc * 32 + fo * 16 + lane15] = f2bf(acc[mh*4+mm][f][j]);
          }
        }
    BAR();
#pragma unroll
    for (int ps = 0; ps < 8; ++ps) {
      int r = ps * 32 + (tid >> 4);
      int grow = m0 + r;
      if (grow < cnt) {
        int cl = (tid & 15) * 8;
        *(s16x8*)&yp[(size_t)(aoff + grow) * HD + n0 + half * 128 + cl] =
            *(const s16x8*)&Ls[r][cl];
      }
    }
  }
}

// ---- combine: out[t] = w0*sum_k yp[k][p0] + w1*sum_k yp[k][p1] ----
__global__ __launch_bounds__(256) void k_combine(
    const u16* __restrict__ yp0, const u16* __restrict__ yp3,
    const int* __restrict__ pos, const float* __restrict__ tw,
    float* __restrict__ out) {
  int t = blockIdx.x;
  int c = threadIdx.x * 4;
  int a0 = pos[t * 2], a1 = pos[t * 2 + 1];
  float w0 = tw[t * 2], w1 = tw[t * 2 + 1];
  float s0[4] = {0.f, 0.f, 0.f, 0.f}, s1[4] = {0.f, 0.f, 0.f, 0.f};
#pragma unroll
  for (int k = 0; k < 4; ++k) {
    const u16* yp = (k < 3) ? yp0 + (size_t)k * AK * HD : yp3;
    ushort4 v0 = *(const ushort4*)&yp[(size_t)a0 * HD + c];
    ushort4 v1 = *(const ushort4*)&yp[(size_t)a1 * HD + c];
    s0[0] += bf2f(v0.x); s0[1] += bf2f(v0.y); s0[2] += bf2f(v0.z); s0[3] += bf2f(v0.w);
    s1[0] += bf2f(v1.x); s1[1] += bf2f(v1.y); s1[2] += bf2f(v1.z); s1[3] += bf2f(v1.w);
  }
  float4 o;
  o.x = w0 * s0[0] + w1 * s1[0];
  o.y = w0 * s0[1] + w1 * s1[1];
  o.z = w0 * s0[2] + w1 * s1[2];
  o.w = w0 * s0[3] + w1 * s1[3];
  *(float4*)&out[(size_t)t * HD + c] = o;
}

// ---------------- host ----------------

extern "C" void kernel_launch(void* const* d_in, const int* in_sizes, int n_in,
                              void* d_out, int out_size, void* d_ws, size_t ws_size,
                              hipStream_t stream) {
  const float* x  = (const float*)d_in[0];
  const float* wg = (const float*)d_in[1];
  const float* w1 = (const float*)d_in[2];
  const float* w2 = (const float*)d_in[3];
  const float* w3 = (const float*)d_in[4];

  char* p = (char*)d_ws;
  auto alloc = [&](size_t bytes) {
    char* r = p;
    p += (bytes + 255) & ~(size_t)255;
    return r;
  };
  u16*   xb      = (u16*)alloc((size_t)T_TOK * HD * 2);           // 16 MiB
  u16*   w13b    = (u16*)alloc((size_t)NE * 2 * ID * HD * 2);     // 128 MiB [E][2I][H]
  u16*   w2b     = (u16*)alloc((size_t)NE * HD * ID * 2);         // 64 MiB  [E][H][I]
  u16*   hidden  = (u16*)alloc((size_t)APAD * ID * 2);            // 130 MiB
  u16*   yp3     = (u16*)alloc((size_t)AK * HD * 2);              // 34 MiB (4th partial)
  int*   tidx    = (int*)alloc(AK * 4);
  float* tw      = (float*)alloc(AK * 4);
  int*   list    = (int*)alloc(AK * 4);
  int*   pos     = (int*)alloc(AK * 4);
  int*   counts  = (int*)alloc(64);
  int*   offs    = (int*)alloc(64);
  int*   cursors = (int*)alloc(64);
  int*   tiles   = (int*)alloc(MTMAX * 4);
  int*   ntile   = (int*)alloc(64);
  (void)ws_size; (void)in_sizes; (void)n_in; (void)out_size;

  u16* yp0 = w13b;   // partials 0..2 alias w13b (dead after gemm1)

  k_init<<<1, 64, 0, stream>>>(counts);
  k_prep<<<NBP_T13 + NBP_RTR, 256, 0, stream>>>(
      x, wg, w1, w3, xb, w13b, tidx, tw, counts);
  k_offsets<<<1, 64, 0, stream>>>(counts, offs, cursors, tiles, ntile);
  k_scatter<<<AK / 256, 256, 0, stream>>>(tidx, offs, cursors, list, pos);

  dim3 gg1(2 * ID / 256, MTMAX + 64, 1);   // y>=MTMAX: 2048 w2-transpose blocks (tail-fill)
  k_gemm1<<<gg1, 512, 0, stream>>>(xb, w13b, list, offs, tiles, ntile, hidden,
                                   w2, w2b);
  dim3 gg2(16, MTMAX, 1);
  k_gemm2<<<gg2, 512, 0, stream>>>(hidden, w2b, offs, tiles, ntile, yp0, yp3);
  k_combine<<<T_TOK, 256, 0, stream>>>(yp0, yp3, pos, tw, (float*)d_out);
}

// Round 11
// 861.821 us; speedup vs baseline: 1.0627x; 1.0095x over previous
//
#include <hip/hip_runtime.h>

typedef unsigned short u16;
typedef __attribute__((ext_vector_type(4))) float f32x4;
typedef __attribute__((ext_vector_type(8))) short s16x8;

#define T_TOK 8192
#define HD    1024
#define ID    4096
#define NE    8
#define AK    (T_TOK * 2)      // total assignments (top-2)
#define APAD  (AK + 256)       // slack rows for 256-row A tiles
#define MTMAX 72               // max M-tiles: 16384/256 + 8 partials

#define BAR()   __builtin_amdgcn_s_barrier()
#define SB0()   __builtin_amdgcn_sched_barrier(0)
#define PRIO1() __builtin_amdgcn_s_setprio(1)
#define PRIO0() __builtin_amdgcn_s_setprio(0)
#define WAITV6() asm volatile("s_waitcnt vmcnt(6)" ::: "memory")
#define WAITV8() asm volatile("s_waitcnt vmcnt(8)" ::: "memory")
#define LGKM0()  do { asm volatile("s_waitcnt lgkmcnt(0)" ::: "memory"); SB0(); } while (0)

__device__ __forceinline__ u16 f2bf(float f) {
  unsigned u = __builtin_bit_cast(unsigned, f);
  u += 0x7FFFu + ((u >> 16) & 1u);   // round-to-nearest-even
  return (u16)(u >> 16);
}

__device__ __forceinline__ float bf2f(u16 v) {
  unsigned u = (unsigned)v << 16;
  return __builtin_bit_cast(float, u);
}

__device__ __forceinline__ void gld16(u16* lds, const u16* g) {
  __builtin_amdgcn_global_load_lds(
      (const __attribute__((address_space(1))) unsigned int*)g,
      (__attribute__((address_space(3))) unsigned int*)lds, 16, 0, 0);
}

// Derive (e, m0, aoff, cnt) for flat M-tile ti from the 8-int counts.
__device__ __forceinline__ int decode_tile(const int* __restrict__ counts,
                                           int ti, int& e, int& m0,
                                           int& aoff, int& cnt) {
  int s = 0;
  for (int ee = 0; ee < NE; ++ee) {
    int c = counts[ee];
    int nt = (c + 255) >> 8;
    if (ti < nt) { e = ee; m0 = ti << 8; aoff = s; cnt = c; return 1; }
    ti -= nt; s += c;
  }
  return 0;
}

// ---------------- scatter (derives offs from counts) ----------------

__global__ __launch_bounds__(256) void k_scatter(
    const int* __restrict__ tidx, const int* __restrict__ counts,
    int* cursors, int* __restrict__ list, int* __restrict__ pos) {
  int idx = blockIdx.x * 256 + threadIdx.x;
  if (idx >= AK) return;
  int e = tidx[idx];
  int off = 0;
  for (int ee = 0; ee < NE; ++ee) off += (ee < e) ? counts[ee] : 0;
  int p = atomicAdd(&cursors[e], 1);
  int a = off + p;
  list[a] = idx >> 1;
  pos[idx] = a;
}

// ---------------- prep: w13 transpose + router(+xb) in one grid ----------------

#define NBP_T13 4096    // 2E(16) x H/256(4) x I/64(64)
#define NBP_RTR 2048

__global__ __launch_bounds__(256) void k_prep(
    const float* __restrict__ x, const float* __restrict__ wg,
    const float* __restrict__ w1, const float* __restrict__ w3,
    u16* __restrict__ xb, u16* __restrict__ w13b,
    int* __restrict__ tidx, float* __restrict__ tw, int* __restrict__ counts) {
  __shared__ char smem[256 * 72 * 2];        // 36 KB (router uses 32 KB)
  int bid = blockIdx.x, t = threadIdx.x;

  if (bid < NBP_T13) {                       // ---- w1/w3 [H][I] -> w13b [2I][H]
    u16 (*tile)[72] = (u16(*)[72])smem;
    int bx = bid & 63;                       // I/64
    int by = (bid >> 6) & 3;                 // H/256
    int bz = bid >> 8;                       // 0..15 = 2E
    int which = bz >> 3, e = bz & 7;
    const float* in = (which ? w3 : w1) + (size_t)e * HD * ID;
    int r0 = by * 256, c0 = bx * 64;
    int rr = t >> 4, cc4 = (t & 15) * 4;
#pragma unroll
    for (int i = 0; i < 16; ++i) {
      int r = i * 16 + rr;
      float4 v = *(const float4*)&in[(size_t)(r0 + r) * ID + c0 + cc4];
      ushort4 bv;
      bv.x = f2bf(v.x); bv.y = f2bf(v.y); bv.z = f2bf(v.z); bv.w = f2bf(v.w);
      *(ushort4*)&tile[r][cc4] = bv;
    }
    __syncthreads();
    int w = t >> 6, c = t & 63;
    int gc = c0 + c;
    int orow = ((gc >> 4) << 5) + which * 16 + (gc & 15);
    u16* obase = w13b + ((size_t)e * 2 * ID + orow) * HD + r0 + w * 64;
#pragma unroll
    for (int j = 0; j < 8; ++j) {
      s16x8 o;
#pragma unroll
      for (int q = 0; q < 8; ++q) o[q] = (short)tile[w * 64 + j * 8 + q][c];
      *(s16x8*)&obase[j * 8] = o;
    }
    return;
  }
  {                                          // ---- router + xb emit
    float* wgs = (float*)smem;               // [e][h] transposed, 32 KB
    int blockR = bid - NBP_T13;
    for (int i = t; i < NE * HD; i += 256) {
      int h = i >> 3, e = i & 7;
      wgs[e * HD + h] = wg[i];
    }
    __syncthreads();
    int lane = t & 63, wid = t >> 6;
    int tok = blockR * 4 + wid;
    const float* xr = x + (size_t)tok * HD;
    u16* xo = xb + (size_t)tok * HD;
    double acc[NE];
#pragma unroll
    for (int e = 0; e < NE; ++e) acc[e] = 0.0;
    for (int i = 0; i < HD / 64; ++i) {
      float xv = xr[lane + i * 64];
      xo[lane + i * 64] = f2bf(xv);
#pragma unroll
      for (int e = 0; e < NE; ++e)
        acc[e] += (double)xv * (double)wgs[e * HD + lane + i * 64];
    }
#pragma unroll
    for (int e = 0; e < NE; ++e)
      for (int s = 32; s >= 1; s >>= 1) acc[e] += __shfl_xor(acc[e], s, 64);
    int e0 = 0; double m0 = acc[0];
    for (int e = 1; e < NE; ++e) if (acc[e] > m0) { m0 = acc[e]; e0 = e; }
    int e1 = -1; double m1 = -1e300;
    for (int e = 0; e < NE; ++e) if (e != e0 && acc[e] > m1) { m1 = acc[e]; e1 = e; }
    if (lane == 0) {
      double d = exp(m1 - m0);
      tidx[tok * 2] = e0; tidx[tok * 2 + 1] = e1;
      tw[tok * 2] = (float)(1.0 / (1.0 + d));
      tw[tok * 2 + 1] = (float)(d / (1.0 + d));
      atomicAdd(&counts[e0], 1);
      atomicAdd(&counts[e1], 1);
    }
  }
}

// ============ 8-phase GEMM core (256x256x64, 8 waves 2Mx4N) ============

#define GEMM_CORE(NTK, NITER) \
  int wr = wid >> 2, wc = wid & 3; \
  int lane15 = lane & 15, lq = lane >> 4, sw8 = lane15 & 7; \
  f32x4 acc[8][4]; \
  _Pragma("unroll") for (int m = 0; m < 8; ++m) \
    _Pragma("unroll") for (int n = 0; n < 4; ++n) acc[m][n] = (f32x4){0.f,0.f,0.f,0.f}; \
  auto stgA = [&](int bb, int h, int kt) { \
    gld16(&As[bb][(h*128 + 0*64 + wid*8) * 64], gA[h*2+0] + kt*64); \
    gld16(&As[bb][(h*128 + 1*64 + wid*8) * 64], gA[h*2+1] + kt*64); }; \
  auto stgB = [&](int bb, int h, int kt) { \
    gld16(&Bs[bb][(h*128 + 0*64 + wid*8) * 64], gB[h*2+0] + kt*64); \
    gld16(&Bs[bb][(h*128 + 1*64 + wid*8) * 64], gB[h*2+1] + kt*64); }; \
  s16x8 a[4][2], b[4][2]; \
  auto rdA = [&](int bb, int mh) { \
    _Pragma("unroll") for (int mm = 0; mm < 4; ++mm) \
      _Pragma("unroll") for (int kk = 0; kk < 2; ++kk) \
        a[mm][kk] = *(const s16x8*)&As[bb][(mh*128 + wr*64 + mm*16 + lane15)*64 + (((kk*4+lq)^sw8)*8)]; }; \
  auto rdB = [&](int bb, int fh) { \
    _Pragma("unroll") for (int ff = 0; ff < 2; ++ff) \
      _Pragma("unroll") for (int kk = 0; kk < 2; ++kk) \
        b[fh*2+ff][kk] = *(const s16x8*)&Bs[bb][(fh*128 + wc*32 + ff*16 + lane15)*64 + (((kk*4+lq)^sw8)*8)]; }; \
  auto mf = [&](int mh, int fh) { \
    _Pragma("unroll") for (int kk = 0; kk < 2; ++kk) \
      _Pragma("unroll") for (int mm = 0; mm < 4; ++mm) \
        _Pragma("unroll") for (int ff = 0; ff < 2; ++ff) \
          acc[mh*4+mm][fh*2+ff] = __builtin_amdgcn_mfma_f32_16x16x32_bf16(a[mm][kk], b[fh*2+ff][kk], acc[mh*4+mm][fh*2+ff], 0, 0, 0); }; \
  /* prologue */ \
  stgA(0,0,0); stgB(0,0,0); stgA(0,1,0); stgB(0,1,0); stgA(1,0,1); stgB(1,0,1); \
  WAITV8(); BAR(); SB0(); \
  for (int i = 0; i < (NITER); ++i) { \
    int ku2 = (2*i+2) & ((NTK)-1), ku3 = (2*i+3) & ((NTK)-1); \
    /* p1 */ rdA(0,0); rdB(0,0); stgA(1,1,2*i+1); WAITV6(); BAR(); LGKM0(); PRIO1(); mf(0,0); PRIO0(); BAR(); SB0(); \
    /* p2 */ rdB(0,1); stgB(1,1,2*i+1); BAR(); LGKM0(); PRIO1(); mf(0,1); PRIO0(); BAR(); SB0(); \
    /* p3 */ rdA(0,1); stgA(0,0,ku2); BAR(); LGKM0(); PRIO1(); mf(1,0); PRIO0(); BAR(); SB0(); \
    /* p4 */ stgB(0,0,ku2); WAITV8(); BAR(); PRIO1(); mf(1,1); PRIO0(); BAR(); SB0(); \
    /* p5 */ rdA(1,0); rdB(1,0); stgA(0,1,ku2); WAITV6(); BAR(); LGKM0(); PRIO1(); mf(0,0); PRIO0(); BAR(); SB0(); \
    /* p6 */ rdB(1,1); stgB(0,1,ku2); BAR(); LGKM0(); PRIO1(); mf(0,1); PRIO0(); BAR(); SB0(); \
    /* p7 */ rdA(1,1); stgA(1,0,ku3); BAR(); LGKM0(); PRIO1(); mf(1,0); PRIO0(); BAR(); SB0(); \
    /* p8 */ stgB(1,0,ku3); WAITV8(); BAR(); PRIO1(); mf(1,1); PRIO0(); BAR(); SB0(); \
  }

#define NGEMM1 (32 * MTMAX)     // 2304 = 8 * 288
#define NGEMM2 (16 * MTMAX)     // 1152 = 8 * 144

// ---- GEMM1 (XCD-chunked, ti-fastest) + tail-fused w2 transpose ----
__global__ __launch_bounds__(512, 1) void k_gemm1(
    const u16* __restrict__ xb, const u16* __restrict__ w13b,
    const int* __restrict__ list, const int* __restrict__ counts,
    u16* __restrict__ hidden,
    const float* __restrict__ w2, u16* __restrict__ w2b) {
  __shared__ u16 As[2][256 * 64];
  __shared__ u16 Bs[2][256 * 64];
  int tid = threadIdx.x, lane = tid & 63, wid = tid >> 6;
  int bid = blockIdx.x;

  if (bid >= NGEMM1) {                       // ---- w2 transpose (tail-fill)
    u16 (*tile)[64] = (u16(*)[64])&As[0][0];
    int flat = bid - NGEMM1;                 // 0..2047
    int bx = flat & 15, by = (flat >> 4) & 15, e2 = flat >> 8;
    const float* in = w2 + (size_t)e2 * ID * HD;
    u16* outp = w2b + (size_t)e2 * HD * ID;
    int r0 = by * 256, c0 = bx * 64;
    int rr = tid >> 4, cc4 = (tid & 15) * 4;
#pragma unroll
    for (int i = 0; i < 8; ++i) {
      int r = i * 32 + rr;
      float4 v = *(const float4*)&in[(size_t)(r0 + r) * HD + c0 + cc4];
      ushort4 bv;
      bv.x = f2bf(v.x); bv.y = f2bf(v.y); bv.z = f2bf(v.z); bv.w = f2bf(v.w);
      *(ushort4*)&tile[r][cc4] = bv;
    }
    __syncthreads();
    int w = tid >> 6, c = tid & 63;
    u16* obase = outp + (size_t)(c0 + c) * ID + r0 + w * 32;
#pragma unroll
    for (int j = 0; j < 4; ++j) {
      s16x8 o;
#pragma unroll
      for (int q = 0; q < 8; ++q) o[q] = (short)tile[w * 32 + j * 8 + q][c];
      *(s16x8*)&obase[j * 8] = o;
    }
    return;
  }

  // XCD-chunked: chunk c = works [c*288, (c+1)*288) = 4 N-panels x 72 ti.
  int work = (bid & 7) * (NGEMM1 / 8) + (bid >> 3);
  int nx = work / MTMAX;              // B-panel id: reused 72x within chunk (L2)
  int ti = work % MTMAX;
  int e, m0, aoff, cnt;
  if (!decode_tile(counts, ti, e, m0, aoff, cnt)) return;
  int n0 = nx * 256;                  // over 2I interleaved

  int l8 = lane >> 3, c8 = lane & 7;
  int csrc = (c8 ^ l8) * 8;

  const u16* gA[4]; const u16* gB[4];
#pragma unroll
  for (int h = 0; h < 2; ++h)
#pragma unroll
    for (int c = 0; c < 2; ++c) {
      int row = h * 128 + c * 64 + wid * 8 + l8;
      int rr = m0 + row; if (rr > cnt - 1) rr = cnt - 1;
      gA[h*2+c] = xb + (size_t)list[aoff + rr] * HD + csrc;
      gB[h*2+c] = w13b + ((size_t)e * 2 * ID + n0 + row) * HD + csrc;
    }

  GEMM_CORE(HD / 64, HD / 128)

  // epilogue: SwiGLU -> LDS restage -> 16B stores (256B runs)
  u16 (*Ls)[132] = (u16(*)[132])&As[0][0];
  BAR();
#pragma unroll
  for (int mh = 0; mh < 2; ++mh)
#pragma unroll
    for (int mm = 0; mm < 4; ++mm)
#pragma unroll
      for (int j = 0; j < 4; ++j) {
        int rl = mh * 128 + wr * 64 + mm * 16 + lq * 4 + j;
#pragma unroll
        for (int p = 0; p < 2; ++p) {
          float v1 = acc[mh*4+mm][2*p][j];
          float v3 = acc[mh*4+mm][2*p+1][j];
          float s = v1 / (1.0f + __expf(-v1));
          Ls[rl][p * 64 + wc * 16 + lane15] = f2bf(s * v3);
        }
      }
  BAR();
#pragma unroll
  for (int ps = 0; ps < 8; ++ps) {
    int r = ps * 32 + (tid >> 4);
    int grow = m0 + r;
    if (grow < cnt) {
      int cl = (tid & 15) * 8;
      *(s16x8*)&hidden[(size_t)(aoff + grow) * ID + (n0 >> 1) + cl] =
          *(const s16x8*)&Ls[r][cl];
    }
  }
}

// ---- GEMM2 (XCD-chunked): yp[kchunk][a] = hidden_chunk @ w2_chunk ----
__global__ __launch_bounds__(512, 1) void k_gemm2(
    const u16* __restrict__ hidden, const u16* __restrict__ w2b,
    const int* __restrict__ counts,
    u16* __restrict__ yp0, u16* __restrict__ yp3) {
  int bid = blockIdx.x;
  int work = (bid & 7) * (NGEMM2 / 8) + (bid >> 3);
  int px = work / MTMAX;              // B-panel id (n0,kc): reused 72x in chunk
  int ti = work % MTMAX;
  int e, m0, aoff, cnt;
  if (!decode_tile(counts, ti, e, m0, aoff, cnt)) return;
  int n0 = (px & 3) * 256;            // H cols
  int kidx = px >> 2;
  int kc = kidx * 1024;               // K chunk base (elements)

  __shared__ u16 As[2][256 * 64];
  __shared__ u16 Bs[2][256 * 64];

  int tid = threadIdx.x, lane = tid & 63, wid = tid >> 6;
  int l8 = lane >> 3, c8 = lane & 7;
  int csrc = (c8 ^ l8) * 8;

  const u16* gA[4]; const u16* gB[4];
#pragma unroll
  for (int h = 0; h < 2; ++h)
#pragma unroll
    for (int c = 0; c < 2; ++c) {
      int row = h * 128 + c * 64 + wid * 8 + l8;
      gA[h*2+c] = hidden + (size_t)(aoff + m0 + row) * ID + kc + csrc;  // APAD slack
      gB[h*2+c] = w2b + ((size_t)e * HD + n0 + row) * ID + kc + csrc;
    }

  GEMM_CORE(1024 / 64, 1024 / 128)

  u16* yp = (kidx < 3) ? yp0 + (size_t)kidx * AK * HD : yp3;
  u16 (*Ls)[132] = (u16(*)[132])&As[0][0];
#pragma unroll
  for (int half = 0; half < 2; ++half) {
    BAR();
#pragma unroll
    for (int mh = 0; mh < 2; ++mh)
#pragma unroll
      for (int mm = 0; mm < 4; ++mm)
#pragma unroll
        for (int j = 0; j < 4; ++j) {
          int rl = mh * 128 + wr * 64 + mm * 16 + lq * 4 + j;
#pragma unroll
          for (int fo = 0; fo < 2; ++fo) {
            int f = half * 2 + fo;
            Ls[rl][wc * 32 + fo * 16 + lane15] = f2bf(acc[mh*4+mm][f][j]);
          }
        }
    BAR();
#pragma unroll
    for (int ps = 0; ps < 8; ++ps) {
      int r = ps * 32 + (tid >> 4);
      int grow = m0 + r;
      if (grow < cnt) {
        int cl = (tid & 15) * 8;
        *(s16x8*)&yp[(size_t)(aoff + grow) * HD + n0 + half * 128 + cl] =
            *(const s16x8*)&Ls[r][cl];
      }
    }
  }
}

// ---- combine: out[t] = w0*sum_k yp[k][p0] + w1*sum_k yp[k][p1] ----
__global__ __launch_bounds__(256) void k_combine(
    const u16* __restrict__ yp0, const u16* __restrict__ yp3,
    const int* __restrict__ pos, const float* __restrict__ tw,
    float* __restrict__ out) {
  int t = blockIdx.x;
  int c = threadIdx.x * 4;
  int a0 = pos[t * 2], a1 = pos[t * 2 + 1];
  float w0 = tw[t * 2], w1 = tw[t * 2 + 1];
  float s0[4] = {0.f, 0.f, 0.f, 0.f}, s1[4] = {0.f, 0.f, 0.f, 0.f};
#pragma unroll
  for (int k = 0; k < 4; ++k) {
    const u16* yp = (k < 3) ? yp0 + (size_t)k * AK * HD : yp3;
    ushort4 v0 = *(const ushort4*)&yp[(size_t)a0 * HD + c];
    ushort4 v1 = *(const ushort4*)&yp[(size_t)a1 * HD + c];
    s0[0] += bf2f(v0.x); s0[1] += bf2f(v0.y); s0[2] += bf2f(v0.z); s0[3] += bf2f(v0.w);
    s1[0] += bf2f(v1.x); s1[1] += bf2f(v1.y); s1[2] += bf2f(v1.z); s1[3] += bf2f(v1.w);
  }
  float4 o;
  o.x = w0 * s0[0] + w1 * s1[0];
  o.y = w0 * s0[1] + w1 * s1[1];
  o.z = w0 * s0[2] + w1 * s1[2];
  o.w = w0 * s0[3] + w1 * s1[3];
  *(float4*)&out[(size_t)t * HD + c] = o;
}

// ---------------- host ----------------

extern "C" void kernel_launch(void* const* d_in, const int* in_sizes, int n_in,
                              void* d_out, int out_size, void* d_ws, size_t ws_size,
                              hipStream_t stream) {
  const float* x  = (const float*)d_in[0];
  const float* wg = (const float*)d_in[1];
  const float* w1 = (const float*)d_in[2];
  const float* w2 = (const float*)d_in[3];
  const float* w3 = (const float*)d_in[4];

  char* p = (char*)d_ws;
  auto alloc = [&](size_t bytes) {
    char* r = p;
    p += (bytes + 255) & ~(size_t)255;
    return r;
  };
  u16*   xb      = (u16*)alloc((size_t)T_TOK * HD * 2);           // 16 MiB
  u16*   w13b    = (u16*)alloc((size_t)NE * 2 * ID * HD * 2);     // 128 MiB [E][2I][H]
  u16*   w2b     = (u16*)alloc((size_t)NE * HD * ID * 2);         // 64 MiB  [E][H][I]
  u16*   hidden  = (u16*)alloc((size_t)APAD * ID * 2);            // 130 MiB
  u16*   yp3     = (u16*)alloc((size_t)AK * HD * 2);              // 34 MiB (4th partial)
  int*   tidx    = (int*)alloc(AK * 4);
  float* tw      = (float*)alloc(AK * 4);
  int*   list    = (int*)alloc(AK * 4);
  int*   pos     = (int*)alloc(AK * 4);
  int*   counts  = (int*)alloc(64);    // counts[0..7] + cursors[8..15] contiguous
  int*   cursors = counts + 8;
  (void)ws_size; (void)in_sizes; (void)n_in; (void)out_size;

  u16* yp0 = w13b;   // partials 0..2 alias w13b (dead after gemm1)

  hipMemsetAsync(counts, 0, 64, stream);
  k_prep<<<NBP_T13 + NBP_RTR, 256, 0, stream>>>(
      x, wg, w1, w3, xb, w13b, tidx, tw, counts);
  k_scatter<<<AK / 256, 256, 0, stream>>>(tidx, counts, cursors, list, pos);

  k_gemm1<<<NGEMM1 + 2048, 512, 0, stream>>>(xb, w13b, list, counts, hidden,
                                             w2, w2b);
  k_gemm2<<<NGEMM2, 512, 0, stream>>>(hidden, w2b, counts, yp0, yp3);
  k_combine<<<T_TOK, 256, 0, stream>>>(yp0, yp3, pos, tw, (float*)d_out);
}